// Round 13
// baseline (2834.141 us; speedup 1.0000x reference)
//
#include <hip/hip_runtime.h>

// Problem constants
#define Bb 128
#define Tt 512
#define Dd 1024
#define Hh 1024
#define KC 2048   // D + H (old fallback path)
#define NG 4096   // 4*H, gate-interleaved: n = 4*j + g
#define BH (Bb * Hh)

typedef __attribute__((ext_vector_type(4))) float f32x4;
typedef __attribute__((ext_vector_type(8))) short s16x8;

__device__ inline unsigned short f2bf(float f) {
  union { float f; unsigned int u; } x;
  x.f = f;
  unsigned int r = x.u + 0x7fffu + ((x.u >> 16) & 1u);  // RNE
  return (unsigned short)(r >> 16);
}
__device__ inline float bf2f(unsigned short u) {
  union { unsigned int u; float f; } x;
  x.u = ((unsigned int)u) << 16;
  return x.f;
}
__device__ inline float sigm(float x) {
  return __builtin_amdgcn_rcpf(1.f + __expf(-x));
}
__device__ inline float tanh_fast(float x) {
  return 2.f * __builtin_amdgcn_rcpf(1.f + __expf(-2.f * x)) - 1.f;
}
// async 16B global -> LDS (wave-uniform LDS base + lane*16 HW scatter; global
// source address is per-lane)
__device__ __forceinline__ void gl_lds16(void* lds, const void* g) {
  __builtin_amdgcn_global_load_lds(
      (const __attribute__((address_space(1))) unsigned int*)g,
      (__attribute__((address_space(3))) unsigned int*)lds, 16, 0, 0);
}

// ============================== NEW PATH =====================================

// Build gate-interleaved bf16 W_ih / W_hh, reordered bias, optional bf16 copy
// of X, zero h-carrier and counters.
__global__ void prep_new(const float* __restrict__ Wih,
                         const float* __restrict__ Whh,
                         const float* __restrict__ bias,
                         const float* __restrict__ X,
                         unsigned short* __restrict__ Wihr,
                         unsigned short* __restrict__ Whhr,
                         unsigned short* __restrict__ xbf,   // nullable
                         float* __restrict__ br,
                         unsigned short* __restrict__ hbf0,
                         unsigned int* __restrict__ cnt) {
  long tid0 = (long)blockIdx.x * blockDim.x + threadIdx.x;
  long stride = (long)gridDim.x * blockDim.x;
  const long wtot = (long)NG * 1024;
  for (long i = tid0; i < wtot; i += stride) {
    int n = (int)(i >> 10), k = (int)(i & 1023);
    int j = n >> 2, g = n & 3;
    Wihr[i] = f2bf(Wih[(size_t)(g * Hh + j) * Dd + k]);
    Whhr[i] = f2bf(Whh[(size_t)(g * Hh + j) * Hh + k]);
  }
  if (xbf) {
    const long xv = (long)Bb * Tt * Dd / 4;  // float4 count
    const float4* xs = (const float4*)X;
    for (long i = tid0; i < xv; i += stride) {
      float4 v = xs[i];
      unsigned int lo = (unsigned int)f2bf(v.x) | ((unsigned int)f2bf(v.y) << 16);
      unsigned int hi = (unsigned int)f2bf(v.z) | ((unsigned int)f2bf(v.w) << 16);
      uint2 p; p.x = lo; p.y = hi;
      *(uint2*)(xbf + 4 * i) = p;
    }
  }
  for (long i = tid0; i < NG; i += stride) {
    int j = (int)i >> 2, g = (int)i & 3;
    br[i] = bias[g * Hh + j];
  }
  for (long i = tid0; i < (long)Bb * Hh; i += stride) hbf0[i] = 0;
  for (long i = tid0; i < 8192; i += stride) cnt[i] = 0u;
}

// xp = X @ Wihr^T (f32 A staged through registers). Verified rounds 2-12.
__global__ __launch_bounds__(256)
void xproj_gemm(const float* __restrict__ X,
                const unsigned short* __restrict__ Wr,
                unsigned short* __restrict__ xp) {
  __shared__ unsigned short As[128 * 64];
  __shared__ unsigned short Bs[128 * 64];
  const int tid = threadIdx.x;
  const int lane = tid & 63, wave = tid >> 6;
  const int wr = wave >> 1, wc = wave & 1;

  int bid = blockIdx.x;
  int id2 = (bid & 7) * (16384 / 8) + (bid >> 3);
  const int m0 = (id2 >> 5) * 128;
  const int n0 = (id2 & 31) * 128;

  f32x4 acc[4][4];
#pragma unroll
  for (int m = 0; m < 4; m++)
#pragma unroll
    for (int n = 0; n < 4; n++) acc[m][n] = (f32x4){0.f, 0.f, 0.f, 0.f};

  const int arow = tid >> 1, ahalf = tid & 1;
  const float* abase = X + (size_t)(m0 + arow) * 1024 + ahalf * 32;

  for (int kc = 0; kc < 1024; kc += 64) {
#pragma unroll
    for (int r = 0; r < 4; r++) {
      int ch = wave * 4 + r;
      int row = ch * 8 + (lane >> 3);
      int slot = (lane & 7) ^ (row & 7);
      gl_lds16((char*)Bs + ch * 1024,
               Wr + (size_t)(n0 + row) * 1024 + kc + slot * 8);
    }
    float4 av[8];
    const float4* asrc = (const float4*)(abase + kc);
#pragma unroll
    for (int i = 0; i < 8; i++) av[i] = asrc[i];
    unsigned short ab[32];
#pragma unroll
    for (int i = 0; i < 8; i++) {
      ab[i * 4 + 0] = f2bf(av[i].x);
      ab[i * 4 + 1] = f2bf(av[i].y);
      ab[i * 4 + 2] = f2bf(av[i].z);
      ab[i * 4 + 3] = f2bf(av[i].w);
    }
#pragma unroll
    for (int i = 0; i < 4; i++) {
      int slot = (ahalf * 4 + i) ^ (arow & 7);
      *(uint4*)((char*)As + arow * 128 + slot * 16) = *(const uint4*)&ab[i * 8];
    }
    __syncthreads();
#pragma unroll
    for (int ks = 0; ks < 2; ks++) {
      s16x8 af[4], bfr[4];
#pragma unroll
      for (int m = 0; m < 4; m++) {
        int row = wr * 64 + m * 16 + (lane & 15);
        int slot = (ks * 4 + (lane >> 4)) ^ (row & 7);
        af[m] = *(const s16x8*)((const char*)As + row * 128 + slot * 16);
      }
#pragma unroll
      for (int n = 0; n < 4; n++) {
        int row = wc * 64 + n * 16 + (lane & 15);
        int slot = (ks * 4 + (lane >> 4)) ^ (row & 7);
        bfr[n] = *(const s16x8*)((const char*)Bs + row * 128 + slot * 16);
      }
#pragma unroll
      for (int m = 0; m < 4; m++)
#pragma unroll
        for (int n = 0; n < 4; n++)
          acc[m][n] = __builtin_amdgcn_mfma_f32_16x16x32_bf16(af[m], bfr[n],
                                                              acc[m][n], 0, 0, 0);
    }
    __syncthreads();
  }

#pragma unroll
  for (int m = 0; m < 4; m++) {
#pragma unroll
    for (int r = 0; r < 4; r++) {
      int gm = m0 + wr * 64 + m * 16 + ((lane >> 4) << 2) + r;
      int t = gm & (Tt - 1), b = gm >> 9;
      unsigned short* dst =
          xp + ((size_t)t * Bb + b) * NG + n0 + wc * 64 + (lane & 15);
#pragma unroll
      for (int n = 0; n < 4; n++) dst[n * 16] = f2bf(acc[m][n][r]);
    }
  }
}

// xp = Xb @ Wihr^T with BOTH operands staged via swizzled global_load_lds
// (m97 structure). Verified rounds 9-12.
__global__ __launch_bounds__(256)
void xproj_gemm2(const unsigned short* __restrict__ Xb,
                 const unsigned short* __restrict__ Wr,
                 unsigned short* __restrict__ xp) {
  __shared__ unsigned short As[128 * 64];
  __shared__ unsigned short Bs[128 * 64];
  const int tid = threadIdx.x;
  const int lane = tid & 63, wave = tid >> 6;
  const int wr = wave >> 1, wc = wave & 1;

  int bid = blockIdx.x;
  int id2 = (bid & 7) * (16384 / 8) + (bid >> 3);
  const int m0 = (id2 >> 5) * 128;
  const int n0 = (id2 & 31) * 128;

  f32x4 acc[4][4];
#pragma unroll
  for (int m = 0; m < 4; m++)
#pragma unroll
    for (int n = 0; n < 4; n++) acc[m][n] = (f32x4){0.f, 0.f, 0.f, 0.f};

  const int grow = lane >> 3;             // 8 rows per 1KB chunk
  const int gslot = lane & 7;

  for (int kc = 0; kc < 1024; kc += 64) {
#pragma unroll
    for (int r = 0; r < 4; r++) {
      int ch = wave * 4 + r;
      int row = ch * 8 + grow;
      int slot = gslot ^ (row & 7);
      gl_lds16((char*)Bs + ch * 1024,
               Wr + (size_t)(n0 + row) * 1024 + kc + slot * 8);
    }
#pragma unroll
    for (int r = 0; r < 4; r++) {
      int ch = wave * 4 + r;
      int row = ch * 8 + grow;
      int slot = gslot ^ (row & 7);
      gl_lds16((char*)As + ch * 1024,
               Xb + (size_t)(m0 + row) * 1024 + kc + slot * 8);
    }
    __syncthreads();
#pragma unroll
    for (int ks = 0; ks < 2; ks++) {
      s16x8 af[4], bfr[4];
#pragma unroll
      for (int m = 0; m < 4; m++) {
        int row = wr * 64 + m * 16 + (lane & 15);
        int slot = (ks * 4 + (lane >> 4)) ^ (row & 7);
        af[m] = *(const s16x8*)((const char*)As + row * 128 + slot * 16);
      }
#pragma unroll
      for (int n = 0; n < 4; n++) {
        int row = wc * 64 + n * 16 + (lane & 15);
        int slot = (ks * 4 + (lane >> 4)) ^ (row & 7);
        bfr[n] = *(const s16x8*)((const char*)Bs + row * 128 + slot * 16);
      }
#pragma unroll
      for (int m = 0; m < 4; m++)
#pragma unroll
        for (int n = 0; n < 4; n++)
          acc[m][n] = __builtin_amdgcn_mfma_f32_16x16x32_bf16(af[m], bfr[n],
                                                              acc[m][n], 0, 0, 0);
    }
    __syncthreads();
  }

#pragma unroll
  for (int m = 0; m < 4; m++) {
#pragma unroll
    for (int r = 0; r < 4; r++) {
      int gm = m0 + wr * 64 + m * 16 + ((lane >> 4) << 2) + r;
      int t = gm & (Tt - 1), b = gm >> 9;
      unsigned short* dst =
          xp + ((size_t)t * Bb + b) * NG + n0 + wc * 64 + (lane & 15);
#pragma unroll
      for (int n = 0; n < 4; n++) dst[n * 16] = f2bf(acc[m][n][r]);
    }
  }
}

// Persistent LSTM recurrence, XCD-local groups — round-12 structure (kh-split
// compute, single vmcnt(0)+barrier, 1605us measured) + sync de-contention:
// STRIPED publish (4 counter lines x 8 WGs, rounds 6/7/9-verified) + 4-lane
// poll, and next-step xq prefetch riding under the spin (vmcnt(1) drains the
// two stores ahead of it; in-order retirement). c lives in registers.
__global__ __launch_bounds__(512, 1)
void lstm_persist(const unsigned short* __restrict__ Whhr,  // [4096][1024] bf16
                  const float* __restrict__ br,             // [4096] reordered
                  const unsigned short* __restrict__ xp,    // [T][128][4096] bf16
                  unsigned short* __restrict__ hb0,         // [128][1024] bf16
                  unsigned short* __restrict__ hb1,
                  float* __restrict__ out,                  // [T][128][1024] ++ dh ++ dc
                  unsigned int* __restrict__ claim,         // [8] spaced 32 uints
                  unsigned int* __restrict__ scnt) {        // [8][4 x 16 uints]
  __shared__ __align__(16) char AsB[16 * 2048];  // h tile [16 rows][128 x16B]
  __shared__ float Gs[2][16][132];               // per-k-half gate partials
  __shared__ unsigned int s_slot;

  const int tid = threadIdx.x;
  const int lane = tid & 63, wave = tid >> 6;  // 8 waves
  const int kh = wave >> 2;                    // k-half
  const int nsl = wave & 3;                    // n-slice (32 gate cols)

  // ---- identify XCD, claim an n-slice ----
  int xcd;
  asm volatile("s_getreg_b32 %0, hwreg(HW_REG_XCC_ID)" : "=s"(xcd));
  xcd &= 7;
  if (tid == 0) {
    s_slot = __hip_atomic_fetch_add(claim + xcd * 32, 1u, __ATOMIC_RELAXED,
                                    __HIP_MEMORY_SCOPE_AGENT);
  }
  __syncthreads();
  const unsigned int slotRaw = s_slot;
  if (slotRaw >= 32u) return;  // uneven dispatch: fail fast, don't hang
  const int slot = (int)slotRaw;
  const int m0 = xcd * 16;
  const int n0 = slot * 128;
  unsigned int* xscnt = scnt + xcd * 64;   // 4 counters, 64B apart

  // ---- W_hh slices into registers: gate rows n0+nsl*32..+31, k-half kh ----
  s16x8 breg0[16], breg1[16];
  {
    const unsigned short* b0 = Whhr +
        (size_t)(n0 + nsl * 32 + (lane & 15)) * 1024 + kh * 512 +
        ((lane >> 4) << 3);
    const unsigned short* b1 = b0 + 16 * 1024;
#pragma unroll
    for (int ks = 0; ks < 16; ks++) {
      breg0[ks] = *(const s16x8*)(b0 + ks * 32);
      breg1[ks] = *(const s16x8*)(b1 + ks * 32);
    }
  }

  // pointwise mapping: thread -> (row, 1 hidden unit)
  const int prow = tid >> 5;          // 0..15
  const int pu = tid & 31;            // 0..31 hidden unit within slice
  const int jg = (n0 >> 2) + pu;
  const float4 bv = *(const float4*)(br + n0 + 4 * pu);
  float creg = 0.f;
  const unsigned short* xpt = xp + (size_t)(m0 + prow) * NG + n0 + 4 * pu;
  const size_t oi = (size_t)(m0 + prow) * Hh + jg;

  const int arow = lane & 15;
  const int arow7 = arow & 7;
  const int klane = lane >> 4;
  const char* abase = AsB + arow * 2048;

  // prologue: xq for t=0
  uint2 xq = *(const uint2*)xpt;

  for (int t = 0; t < Tt; t++) {
    const unsigned short* hin = (t & 1) ? hb1 : hb0;
    unsigned short* hnx = (t & 1) ? hb0 : hb1;

    // ---- stage h tile (32KB): 32 chunks of 1KB, 4 per wave (R4 order) ----
#pragma unroll
    for (int i = 0; i < 4; i++) {
      int ch = wave * 4 + i;
      int row = ch >> 1, half = ch & 1;
      gl_lds16(AsB + row * 2048 + half * 1024,
               hin + (size_t)(m0 + row) * 1024 +
                   (((half * 64 + lane) ^ (row & 7)) << 3));
    }

    f32x4 acc0 = {0.f, 0.f, 0.f, 0.f};
    f32x4 acc1 = {0.f, 0.f, 0.f, 0.f};

    asm volatile("s_waitcnt vmcnt(0)" ::: "memory");
    __builtin_amdgcn_sched_barrier(0);
    __builtin_amdgcn_s_barrier();
    __builtin_amdgcn_sched_barrier(0);

    // 16 ds_read_b128 (this wave's k-half), each feeding two MFMAs
#pragma unroll
    for (int ks2 = 0; ks2 < 16; ks2++) {
      int ks = kh * 16 + ks2;
      s16x8 af = *(const s16x8*)(abase + (((ks * 4 + klane) ^ arow7) << 4));
      acc0 = __builtin_amdgcn_mfma_f32_16x16x32_bf16(af, breg0[ks2], acc0, 0, 0, 0);
      acc1 = __builtin_amdgcn_mfma_f32_16x16x32_bf16(af, breg1[ks2], acc1, 0, 0, 0);
    }

    // ---- acc -> Gs[kh] (C/D layout: col=lane&15, row=(lane>>4)*4+reg) ----
    {
      int colg = nsl * 32 + (lane & 15);
      int rb = (lane >> 4) << 2;
#pragma unroll
      for (int r = 0; r < 4; r++) Gs[kh][rb + r][colg] = acc0[r];
#pragma unroll
      for (int r = 0; r < 4; r++) Gs[kh][rb + r][colg + 16] = acc1[r];
    }
    __syncthreads();

    // ---- pointwise LSTM: 1 hidden unit per thread, c in register ----
    {
      float4 g0 = *(const float4*)&Gs[0][prow][4 * pu];
      float4 g1 = *(const float4*)&Gs[1][prow][4 * pu];
      float iv = g0.x + g1.x + bf2f((unsigned short)(xq.x & 0xffffu)) + bv.x;
      float fv = g0.y + g1.y + bf2f((unsigned short)(xq.x >> 16)) + bv.y;
      float gv = g0.z + g1.z + bf2f((unsigned short)(xq.y & 0xffffu)) + bv.z;
      float ov = g0.w + g1.w + bf2f((unsigned short)(xq.y >> 16)) + bv.w;
      float ig = sigm(iv), fg = sigm(fv), og = sigm(ov);
      float gt = tanh_fast(gv);
      creg = fg * creg + ig * gt;
      float hn = og * tanh_fast(creg);
      // hnx FIRST (the only store other WGs read), then out
      hnx[oi] = f2bf(hn);
      asm volatile("" ::: "memory");
      out[(size_t)t * BH + oi] = hn;
      if (t == Tt - 1) {
        float* dh = out + (size_t)Tt * BH;
        dh[oi] = hn;        // h_last
        dh[BH + oi] = creg; // c_last
      }
    }

    if (t < Tt - 1) {
      // prefetch next step's xq; rides under the sync (issued after stores)
      xq = *(const uint2*)(xpt + (size_t)(t + 1) * (Bb * NG));
      __builtin_amdgcn_sched_barrier(0);
      // drain the two stores (oldest); xq load stays in flight
      asm volatile("s_waitcnt vmcnt(1)" ::: "memory");
      __builtin_amdgcn_sched_barrier(0);
      __builtin_amdgcn_s_barrier();   // all waves' hnx in L2
      __builtin_amdgcn_sched_barrier(0);
      if (tid == 0) {
        __hip_atomic_fetch_add(xscnt + (slot & 3) * 16, 1u, __ATOMIC_RELAXED,
                               __HIP_MEMORY_SCOPE_AGENT);
      }
      if (wave == 0) {
        const unsigned int target = 8u * (unsigned int)(t + 1);
        for (int it = 0; it < (1 << 16); ++it) {
          unsigned int v = target;
          if (lane < 4)
            v = __hip_atomic_load(xscnt + lane * 16, __ATOMIC_RELAXED,
                                  __HIP_MEMORY_SCOPE_AGENT);
          if (__all((int)(v >= target))) break;
          __builtin_amdgcn_s_sleep(1);
        }
        // L1-only invalidate so this CU's next h loads see fresh L2 data
        asm volatile("buffer_inv sc0" ::: "memory");
      }
      __builtin_amdgcn_sched_barrier(0);
      __builtin_amdgcn_s_barrier();   // release all waves into step t+1
      __builtin_amdgcn_sched_barrier(0);
    }
  }
}

// ====================== OLD PATH (fallback, ws-limited) ======================

__global__ void prep_kernel(const float* __restrict__ Wih,
                            const float* __restrict__ Whh,
                            const float* __restrict__ bias,
                            unsigned short* __restrict__ Wr,
                            float* __restrict__ br,
                            float* __restrict__ c) {
  long tid0 = (long)blockIdx.x * blockDim.x + threadIdx.x;
  long stride = (long)gridDim.x * blockDim.x;
  const long total = (long)NG * KC;
  for (long idx = tid0; idx < total; idx += stride) {
    int n = (int)(idx >> 11);
    int k = (int)(idx & (KC - 1));
    int j = n >> 2, g = n & 3;
    float v;
    if (k < Dd) v = Wih[(size_t)(g * Hh + j) * Dd + k];
    else        v = Whh[(size_t)(g * Hh + j) * Hh + (k - Dd)];
    Wr[idx] = f2bf(v);
  }
  for (long idx = tid0; idx < NG; idx += stride) {
    int j = (int)idx >> 2, g = (int)idx & 3;
    br[idx] = bias[g * Hh + j];
  }
  for (long idx = tid0; idx < (long)Bb * Hh; idx += stride)
    c[idx] = 0.f;
}

__global__ __launch_bounds__(256)
void lstm_step(const float* __restrict__ xt,
               const float* __restrict__ hprev,
               const unsigned short* __restrict__ Wr,
               const float* __restrict__ br,
               float* __restrict__ c,
               float* __restrict__ hout) {
  __shared__ unsigned short As2[32][64 + 8];
  __shared__ unsigned short Bs2[64][64 + 8];
  __shared__ float Gs[32][64];

  const int tid = threadIdx.x;
  const int lane = tid & 63;
  const int wid = tid >> 6;
  const int wr = wid >> 1;
  const int wc = wid & 1;
  const int m0 = blockIdx.x * 32;
  const int n0 = blockIdx.y * 64;

  f32x4 acc0 = {0.f, 0.f, 0.f, 0.f};
  f32x4 acc1 = {0.f, 0.f, 0.f, 0.f};

  const int a_row = tid >> 3;
  const int a_k = (tid & 7) << 3;
  const int b_row = tid >> 2;
  const int b_k = (tid & 3) << 4;

  for (int kc = 0; kc < KC; kc += 64) {
    {
      int k = kc + a_k;
      float v[8];
      if (k < Dd) {
        const float4* s =
            (const float4*)(xt + (size_t)(m0 + a_row) * ((size_t)Tt * Dd) + k);
        float4 p0 = s[0], p1 = s[1];
        v[0] = p0.x; v[1] = p0.y; v[2] = p0.z; v[3] = p0.w;
        v[4] = p1.x; v[5] = p1.y; v[6] = p1.z; v[7] = p1.w;
      } else if (hprev) {
        const float4* s =
            (const float4*)(hprev + (size_t)(m0 + a_row) * Hh + (k - Dd));
        float4 p0 = s[0], p1 = s[1];
        v[0] = p0.x; v[1] = p0.y; v[2] = p0.z; v[3] = p0.w;
        v[4] = p1.x; v[5] = p1.y; v[6] = p1.z; v[7] = p1.w;
      } else {
#pragma unroll
        for (int e = 0; e < 8; e++) v[e] = 0.f;
      }
#pragma unroll
      for (int e = 0; e < 8; e++) As2[a_row][a_k + e] = f2bf(v[e]);
    }
    {
      const uint4* s = (const uint4*)(Wr + (size_t)(n0 + b_row) * KC + kc + b_k);
      uint4 p0 = s[0], p1 = s[1];
      *(uint4*)&Bs2[b_row][b_k] = p0;
      *(uint4*)&Bs2[b_row][b_k + 8] = p1;
    }
    __syncthreads();
#pragma unroll
    for (int ks = 0; ks < 64; ks += 32) {
      s16x8 af = *(const s16x8*)&As2[wr * 16 + (lane & 15)][ks + ((lane >> 4) << 3)];
      s16x8 bf0 = *(const s16x8*)&Bs2[wc * 32 + (lane & 15)][ks + ((lane >> 4) << 3)];
      s16x8 bf1 = *(const s16x8*)&Bs2[wc * 32 + 16 + (lane & 15)][ks + ((lane >> 4) << 3)];
      acc0 = __builtin_amdgcn_mfma_f32_16x16x32_bf16(af, bf0, acc0, 0, 0, 0);
      acc1 = __builtin_amdgcn_mfma_f32_16x16x32_bf16(af, bf1, acc1, 0, 0, 0);
    }
    __syncthreads();
  }

  {
    int colb = wc * 32 + (lane & 15);
    int rbase = wr * 16 + ((lane >> 4) << 2);
#pragma unroll
    for (int r = 0; r < 4; r++) Gs[rbase + r][colb] = acc0[r];
#pragma unroll
    for (int r = 0; r < 4; r++) Gs[rbase + r][colb + 16] = acc1[r];
  }
  __syncthreads();

  for (int e = tid; e < 512; e += 256) {
    int row = e >> 4;
    int jc = e & 15;
    int gi = jc << 2;
    float iv = Gs[row][gi + 0] + br[n0 + gi + 0];
    float fv = Gs[row][gi + 1] + br[n0 + gi + 1];
    float gv = Gs[row][gi + 2] + br[n0 + gi + 2];
    float ov = Gs[row][gi + 3] + br[n0 + gi + 3];
    int gb = m0 + row;
    int j = (n0 >> 2) + jc;
    float cv = c[(size_t)gb * Hh + j];
    float ig = 1.f / (1.f + __expf(-iv));
    float fg = 1.f / (1.f + __expf(-fv));
    float og = 1.f / (1.f + __expf(-ov));
    float gg = tanhf(gv);
    float cn = fg * cv + ig * gg;
    float hn = og * tanhf(cn);
    c[(size_t)gb * Hh + j] = cn;
    hout[(size_t)gb * Hh + j] = hn;
  }
}

__global__ void finalize_kernel(const float* __restrict__ hlast,
                                const float* __restrict__ c,
                                float* __restrict__ dh,
                                float* __restrict__ dc) {
  int i = blockIdx.x * 256 + threadIdx.x;
  if (i < Bb * Hh) {
    dh[i] = hlast[i];
    dc[i] = c[i];
  }
}

// ============================== LAUNCHER =====================================

extern "C" void kernel_launch(void* const* d_in, const int* in_sizes, int n_in,
                              void* d_out, int out_size, void* d_ws, size_t ws_size,
                              hipStream_t stream) {
  const float* x = (const float*)d_in[0];     // [B,T,D]
  const float* Wih = (const float*)d_in[1];   // [4H,D]
  const float* Whh = (const float*)d_in[2];   // [4H,H]
  const float* bias = (const float*)d_in[3];  // [4H]
  float* out = (float*)d_out;                 // [T,B,H] ++ [B,H] ++ [B,H]
  char* ws = (char*)d_ws;

  const size_t WHH_OFF = 0;
  const size_t WIH_OFF = 8ull << 20;
  const size_t BR_OFF = 16ull << 20;
  const size_t H0_OFF = 17ull << 20;
  const size_t H1_OFF = (17ull << 20) + (256ull << 10);
  const size_t CNT_OFF = (17ull << 20) + (512ull << 10);
  const size_t XBF_OFF = 18ull << 20;
  const size_t XBF_SZ = (size_t)Bb * Tt * Dd * 2;          // 128 MB
  const size_t XP_SZ = (size_t)Tt * Bb * NG * 2;           // 512 MB
  const size_t NEED_MID = XBF_OFF + XP_SZ;                 // ~530 MB
  const size_t NEED_FULL = XBF_OFF + XBF_SZ + XP_SZ;       // ~658 MB

  if (ws_size >= NEED_MID) {
    const bool full = (ws_size >= NEED_FULL);
    unsigned short* Whhr = (unsigned short*)(ws + WHH_OFF);
    unsigned short* Wihr = (unsigned short*)(ws + WIH_OFF);
    float* br = (float*)(ws + BR_OFF);
    unsigned short* hb0 = (unsigned short*)(ws + H0_OFF);
    unsigned short* hb1 = (unsigned short*)(ws + H1_OFF);
    unsigned int* cnt = (unsigned int*)(ws + CNT_OFF);   // 8192 uints zeroed
    unsigned short* xbf = full ? (unsigned short*)(ws + XBF_OFF) : nullptr;
    unsigned short* xp =
        (unsigned short*)(ws + XBF_OFF + (full ? XBF_SZ : 0));

    prep_new<<<2048, 256, 0, stream>>>(Wih, Whh, bias, x, Wihr, Whhr, xbf, br,
                                       hb0, cnt);
    if (full)
      xproj_gemm2<<<16384, 256, 0, stream>>>(xbf, Wihr, xp);
    else
      xproj_gemm<<<16384, 256, 0, stream>>>(x, Wihr, xp);
    lstm_persist<<<256, 512, 0, stream>>>(Whhr, br, xp, hb0, hb1, out,
                                          cnt /*claim*/, cnt + 1024 /*scnt*/);
  } else {
    // fallback: round-1 path (16.5 MB ws)
    unsigned short* Wr = (unsigned short*)ws;
    float* br = (float*)(ws + (size_t)NG * KC * 2);
    float* c = (float*)(ws + (size_t)NG * KC * 2 + (size_t)NG * 4);

    prep_kernel<<<1024, 256, 0, stream>>>(Wih, Whh, bias, Wr, br, c);
    dim3 grid(Bb / 32, NG / 64);
    for (int t = 0; t < Tt; t++) {
      const float* xt = x + (size_t)t * Dd;
      const float* hp = (t == 0) ? nullptr : out + (size_t)(t - 1) * Bb * Hh;
      lstm_step<<<grid, 256, 0, stream>>>(xt, hp, Wr, br, c,
                                          out + (size_t)t * Bb * Hh);
    }
    float* dh = out + (size_t)Tt * Bb * Hh;
    finalize_kernel<<<(Bb * Hh + 255) / 256, 256, 0, stream>>>(
        out + (size_t)(Tt - 1) * Bb * Hh, c, dh, dh + (size_t)Bb * Hh);
  }
}

// Round 14
// 2222.835 us; speedup vs baseline: 1.2750x; 1.2750x over previous
//
#include <hip/hip_runtime.h>

// Problem constants
#define Bb 128
#define Tt 512
#define Dd 1024
#define Hh 1024
#define KC 2048   // D + H (old fallback path)
#define NG 4096   // 4*H, gate-interleaved: n = 4*j + g
#define BH (Bb * Hh)

typedef __attribute__((ext_vector_type(4))) float f32x4;
typedef __attribute__((ext_vector_type(8))) short s16x8;

__device__ inline unsigned short f2bf(float f) {
  union { float f; unsigned int u; } x;
  x.f = f;
  unsigned int r = x.u + 0x7fffu + ((x.u >> 16) & 1u);  // RNE
  return (unsigned short)(r >> 16);
}
__device__ inline float bf2f(unsigned short u) {
  union { unsigned int u; float f; } x;
  x.u = ((unsigned int)u) << 16;
  return x.f;
}
__device__ inline float sigm(float x) {
  return __builtin_amdgcn_rcpf(1.f + __expf(-x));
}
__device__ inline float tanh_fast(float x) {
  return 2.f * __builtin_amdgcn_rcpf(1.f + __expf(-2.f * x)) - 1.f;
}
// async 16B global -> LDS (wave-uniform LDS base + lane*16 HW scatter; global
// source address is per-lane)
__device__ __forceinline__ void gl_lds16(void* lds, const void* g) {
  __builtin_amdgcn_global_load_lds(
      (const __attribute__((address_space(1))) unsigned int*)g,
      (__attribute__((address_space(3))) unsigned int*)lds, 16, 0, 0);
}

// ============================== NEW PATH =====================================

// Build gate-interleaved bf16 W_ih / W_hh, reordered bias, optional bf16 copy
// of X, zero h-carrier and counters.
__global__ void prep_new(const float* __restrict__ Wih,
                         const float* __restrict__ Whh,
                         const float* __restrict__ bias,
                         const float* __restrict__ X,
                         unsigned short* __restrict__ Wihr,
                         unsigned short* __restrict__ Whhr,
                         unsigned short* __restrict__ xbf,   // nullable
                         float* __restrict__ br,
                         unsigned short* __restrict__ hbf0,
                         unsigned int* __restrict__ cnt) {
  long tid0 = (long)blockIdx.x * blockDim.x + threadIdx.x;
  long stride = (long)gridDim.x * blockDim.x;
  const long wtot = (long)NG * 1024;
  for (long i = tid0; i < wtot; i += stride) {
    int n = (int)(i >> 10), k = (int)(i & 1023);
    int j = n >> 2, g = n & 3;
    Wihr[i] = f2bf(Wih[(size_t)(g * Hh + j) * Dd + k]);
    Whhr[i] = f2bf(Whh[(size_t)(g * Hh + j) * Hh + k]);
  }
  if (xbf) {
    const long xv = (long)Bb * Tt * Dd / 4;  // float4 count
    const float4* xs = (const float4*)X;
    for (long i = tid0; i < xv; i += stride) {
      float4 v = xs[i];
      unsigned int lo = (unsigned int)f2bf(v.x) | ((unsigned int)f2bf(v.y) << 16);
      unsigned int hi = (unsigned int)f2bf(v.z) | ((unsigned int)f2bf(v.w) << 16);
      uint2 p; p.x = lo; p.y = hi;
      *(uint2*)(xbf + 4 * i) = p;
    }
  }
  for (long i = tid0; i < NG; i += stride) {
    int j = (int)i >> 2, g = (int)i & 3;
    br[i] = bias[g * Hh + j];
  }
  for (long i = tid0; i < (long)Bb * Hh; i += stride) hbf0[i] = 0;
  for (long i = tid0; i < 8192; i += stride) cnt[i] = 0u;
}

// xp = X @ Wihr^T (f32 A staged through registers). Verified rounds 2-13.
__global__ __launch_bounds__(256)
void xproj_gemm(const float* __restrict__ X,
                const unsigned short* __restrict__ Wr,
                unsigned short* __restrict__ xp) {
  __shared__ unsigned short As[128 * 64];
  __shared__ unsigned short Bs[128 * 64];
  const int tid = threadIdx.x;
  const int lane = tid & 63, wave = tid >> 6;
  const int wr = wave >> 1, wc = wave & 1;

  int bid = blockIdx.x;
  int id2 = (bid & 7) * (16384 / 8) + (bid >> 3);
  const int m0 = (id2 >> 5) * 128;
  const int n0 = (id2 & 31) * 128;

  f32x4 acc[4][4];
#pragma unroll
  for (int m = 0; m < 4; m++)
#pragma unroll
    for (int n = 0; n < 4; n++) acc[m][n] = (f32x4){0.f, 0.f, 0.f, 0.f};

  const int arow = tid >> 1, ahalf = tid & 1;
  const float* abase = X + (size_t)(m0 + arow) * 1024 + ahalf * 32;

  for (int kc = 0; kc < 1024; kc += 64) {
#pragma unroll
    for (int r = 0; r < 4; r++) {
      int ch = wave * 4 + r;
      int row = ch * 8 + (lane >> 3);
      int slot = (lane & 7) ^ (row & 7);
      gl_lds16((char*)Bs + ch * 1024,
               Wr + (size_t)(n0 + row) * 1024 + kc + slot * 8);
    }
    float4 av[8];
    const float4* asrc = (const float4*)(abase + kc);
#pragma unroll
    for (int i = 0; i < 8; i++) av[i] = asrc[i];
    unsigned short ab[32];
#pragma unroll
    for (int i = 0; i < 8; i++) {
      ab[i * 4 + 0] = f2bf(av[i].x);
      ab[i * 4 + 1] = f2bf(av[i].y);
      ab[i * 4 + 2] = f2bf(av[i].z);
      ab[i * 4 + 3] = f2bf(av[i].w);
    }
#pragma unroll
    for (int i = 0; i < 4; i++) {
      int slot = (ahalf * 4 + i) ^ (arow & 7);
      *(uint4*)((char*)As + arow * 128 + slot * 16) = *(const uint4*)&ab[i * 8];
    }
    __syncthreads();
#pragma unroll
    for (int ks = 0; ks < 2; ks++) {
      s16x8 af[4], bfr[4];
#pragma unroll
      for (int m = 0; m < 4; m++) {
        int row = wr * 64 + m * 16 + (lane & 15);
        int slot = (ks * 4 + (lane >> 4)) ^ (row & 7);
        af[m] = *(const s16x8*)((const char*)As + row * 128 + slot * 16);
      }
#pragma unroll
      for (int n = 0; n < 4; n++) {
        int row = wc * 64 + n * 16 + (lane & 15);
        int slot = (ks * 4 + (lane >> 4)) ^ (row & 7);
        bfr[n] = *(const s16x8*)((const char*)Bs + row * 128 + slot * 16);
      }
#pragma unroll
      for (int m = 0; m < 4; m++)
#pragma unroll
        for (int n = 0; n < 4; n++)
          acc[m][n] = __builtin_amdgcn_mfma_f32_16x16x32_bf16(af[m], bfr[n],
                                                              acc[m][n], 0, 0, 0);
    }
    __syncthreads();
  }

#pragma unroll
  for (int m = 0; m < 4; m++) {
#pragma unroll
    for (int r = 0; r < 4; r++) {
      int gm = m0 + wr * 64 + m * 16 + ((lane >> 4) << 2) + r;
      int t = gm & (Tt - 1), b = gm >> 9;
      unsigned short* dst =
          xp + ((size_t)t * Bb + b) * NG + n0 + wc * 64 + (lane & 15);
#pragma unroll
      for (int n = 0; n < 4; n++) dst[n * 16] = f2bf(acc[m][n][r]);
    }
  }
}

// xp = Xb @ Wihr^T with BOTH operands staged via swizzled global_load_lds
// (m97 structure). Verified rounds 9-13.
__global__ __launch_bounds__(256)
void xproj_gemm2(const unsigned short* __restrict__ Xb,
                 const unsigned short* __restrict__ Wr,
                 unsigned short* __restrict__ xp) {
  __shared__ unsigned short As[128 * 64];
  __shared__ unsigned short Bs[128 * 64];
  const int tid = threadIdx.x;
  const int lane = tid & 63, wave = tid >> 6;
  const int wr = wave >> 1, wc = wave & 1;

  int bid = blockIdx.x;
  int id2 = (bid & 7) * (16384 / 8) + (bid >> 3);
  const int m0 = (id2 >> 5) * 128;
  const int n0 = (id2 & 31) * 128;

  f32x4 acc[4][4];
#pragma unroll
  for (int m = 0; m < 4; m++)
#pragma unroll
    for (int n = 0; n < 4; n++) acc[m][n] = (f32x4){0.f, 0.f, 0.f, 0.f};

  const int grow = lane >> 3;             // 8 rows per 1KB chunk
  const int gslot = lane & 7;

  for (int kc = 0; kc < 1024; kc += 64) {
#pragma unroll
    for (int r = 0; r < 4; r++) {
      int ch = wave * 4 + r;
      int row = ch * 8 + grow;
      int slot = gslot ^ (row & 7);
      gl_lds16((char*)Bs + ch * 1024,
               Wr + (size_t)(n0 + row) * 1024 + kc + slot * 8);
    }
#pragma unroll
    for (int r = 0; r < 4; r++) {
      int ch = wave * 4 + r;
      int row = ch * 8 + grow;
      int slot = gslot ^ (row & 7);
      gl_lds16((char*)As + ch * 1024,
               Xb + (size_t)(m0 + row) * 1024 + kc + slot * 8);
    }
    __syncthreads();
#pragma unroll
    for (int ks = 0; ks < 2; ks++) {
      s16x8 af[4], bfr[4];
#pragma unroll
      for (int m = 0; m < 4; m++) {
        int row = wr * 64 + m * 16 + (lane & 15);
        int slot = (ks * 4 + (lane >> 4)) ^ (row & 7);
        af[m] = *(const s16x8*)((const char*)As + row * 128 + slot * 16);
      }
#pragma unroll
      for (int n = 0; n < 4; n++) {
        int row = wc * 64 + n * 16 + (lane & 15);
        int slot = (ks * 4 + (lane >> 4)) ^ (row & 7);
        bfr[n] = *(const s16x8*)((const char*)Bs + row * 128 + slot * 16);
      }
#pragma unroll
      for (int m = 0; m < 4; m++)
#pragma unroll
        for (int n = 0; n < 4; n++)
          acc[m][n] = __builtin_amdgcn_mfma_f32_16x16x32_bf16(af[m], bfr[n],
                                                              acc[m][n], 0, 0, 0);
    }
    __syncthreads();
  }

#pragma unroll
  for (int m = 0; m < 4; m++) {
#pragma unroll
    for (int r = 0; r < 4; r++) {
      int gm = m0 + wr * 64 + m * 16 + ((lane >> 4) << 2) + r;
      int t = gm & (Tt - 1), b = gm >> 9;
      unsigned short* dst =
          xp + ((size_t)t * Bb + b) * NG + n0 + wc * 64 + (lane & 15);
#pragma unroll
      for (int n = 0; n < 4; n++) dst[n * 16] = f2bf(acc[m][n][r]);
    }
  }
}

// Persistent LSTM recurrence, XCD-local groups — ROUND-12 VERBATIM (best
// measured: 1605us). kh-split compute (halved LDS reads, single barrier):
// 256 WGs x 512 thr. Waves = 4 n-slices (nsl=wave&3) x 2 k-halves
// (kh=wave>>2). Each wave: breg0/breg1[16] = 32 gate cols x its 512-k half;
// reads only its HALF of the 32KB A-tile; 32 MFMAs between ONE
// vmcnt(0)+barrier. Partial sums -> Gs[2] planes; pointwise adds both.
// hnx stored first, out second; vmcnt(1) drains hnx only. Sync: SINGLE
// per-XCD agent-scope counter, tid0 publish + bounded poll, buffer_inv sc0.
// (R13's striped+4-lane-poll+xq-prefetch bundle regressed 35% — reverted.)
__global__ __launch_bounds__(512, 1)
void lstm_persist(const unsigned short* __restrict__ Whhr,  // [4096][1024] bf16
                  const float* __restrict__ br,             // [4096] reordered
                  const unsigned short* __restrict__ xp,    // [T][128][4096] bf16
                  unsigned short* __restrict__ hb0,         // [128][1024] bf16
                  unsigned short* __restrict__ hb1,
                  float* __restrict__ out,                  // [T][128][1024] ++ dh ++ dc
                  unsigned int* __restrict__ claim,         // [8] spaced 32 uints
                  unsigned int* __restrict__ scnt) {        // [8] spaced 32 uints
  __shared__ __align__(16) char AsB[16 * 2048];  // h tile [16 rows][128 x16B]
  __shared__ float Gs[2][16][132];               // per-k-half gate partials
  __shared__ unsigned int s_slot;

  const int tid = threadIdx.x;
  const int lane = tid & 63, wave = tid >> 6;  // 8 waves
  const int kh = wave >> 2;                    // k-half
  const int nsl = wave & 3;                    // n-slice (32 gate cols)

  // ---- identify XCD, claim an n-slice ----
  int xcd;
  asm volatile("s_getreg_b32 %0, hwreg(HW_REG_XCC_ID)" : "=s"(xcd));
  xcd &= 7;
  if (tid == 0) {
    s_slot = __hip_atomic_fetch_add(claim + xcd * 32, 1u, __ATOMIC_RELAXED,
                                    __HIP_MEMORY_SCOPE_AGENT);
  }
  __syncthreads();
  const unsigned int slotRaw = s_slot;
  if (slotRaw >= 32u) return;  // uneven dispatch: fail fast, don't hang
  const int slot = (int)slotRaw;
  const int m0 = xcd * 16;
  const int n0 = slot * 128;
  unsigned int* mycnt = scnt + xcd * 32;

  // ---- W_hh slices into registers: gate rows n0+nsl*32..+31, k-half kh ----
  s16x8 breg0[16], breg1[16];
  {
    const unsigned short* b0 = Whhr +
        (size_t)(n0 + nsl * 32 + (lane & 15)) * 1024 + kh * 512 +
        ((lane >> 4) << 3);
    const unsigned short* b1 = b0 + 16 * 1024;
#pragma unroll
    for (int ks = 0; ks < 16; ks++) {
      breg0[ks] = *(const s16x8*)(b0 + ks * 32);
      breg1[ks] = *(const s16x8*)(b1 + ks * 32);
    }
  }

  // pointwise mapping: thread -> (row, 1 hidden unit)
  const int prow = tid >> 5;          // 0..15
  const int pu = tid & 31;            // 0..31 hidden unit within slice
  const int jg = (n0 >> 2) + pu;
  const float4 bv = *(const float4*)(br + n0 + 4 * pu);
  float creg = 0.f;
  const unsigned short* xpt = xp + (size_t)(m0 + prow) * NG + n0 + 4 * pu;
  const size_t oi = (size_t)(m0 + prow) * Hh + jg;

  const int arow = lane & 15;
  const int arow7 = arow & 7;
  const int klane = lane >> 4;
  const char* abase = AsB + arow * 2048;

  for (int t = 0; t < Tt; t++) {
    const unsigned short* hin = (t & 1) ? hb1 : hb0;
    unsigned short* hnx = (t & 1) ? hb0 : hb1;

    // xp slice for this step (issued early; consumed in pointwise)
    uint2 xq = *(const uint2*)(xpt + (size_t)t * (Bb * NG));

    // ---- stage h tile (32KB): 32 chunks of 1KB, 4 per wave (R4 order) ----
#pragma unroll
    for (int i = 0; i < 4; i++) {
      int ch = wave * 4 + i;
      int row = ch >> 1, half = ch & 1;
      gl_lds16(AsB + row * 2048 + half * 1024,
               hin + (size_t)(m0 + row) * 1024 +
                   (((half * 64 + lane) ^ (row & 7)) << 3));
    }

    f32x4 acc0 = {0.f, 0.f, 0.f, 0.f};
    f32x4 acc1 = {0.f, 0.f, 0.f, 0.f};

    asm volatile("s_waitcnt vmcnt(0)" ::: "memory");
    __builtin_amdgcn_sched_barrier(0);
    __builtin_amdgcn_s_barrier();
    __builtin_amdgcn_sched_barrier(0);

    // 16 ds_read_b128 (this wave's k-half), each feeding two MFMAs
#pragma unroll
    for (int ks2 = 0; ks2 < 16; ks2++) {
      int ks = kh * 16 + ks2;
      s16x8 af = *(const s16x8*)(abase + (((ks * 4 + klane) ^ arow7) << 4));
      acc0 = __builtin_amdgcn_mfma_f32_16x16x32_bf16(af, breg0[ks2], acc0, 0, 0, 0);
      acc1 = __builtin_amdgcn_mfma_f32_16x16x32_bf16(af, breg1[ks2], acc1, 0, 0, 0);
    }

    // ---- acc -> Gs[kh] (C/D layout: col=lane&15, row=(lane>>4)*4+reg) ----
    {
      int colg = nsl * 32 + (lane & 15);
      int rb = (lane >> 4) << 2;
#pragma unroll
      for (int r = 0; r < 4; r++) Gs[kh][rb + r][colg] = acc0[r];
#pragma unroll
      for (int r = 0; r < 4; r++) Gs[kh][rb + r][colg + 16] = acc1[r];
    }
    __syncthreads();

    // ---- pointwise LSTM: 1 hidden unit per thread, c in register ----
    {
      float4 g0 = *(const float4*)&Gs[0][prow][4 * pu];
      float4 g1 = *(const float4*)&Gs[1][prow][4 * pu];
      float iv = g0.x + g1.x + bf2f((unsigned short)(xq.x & 0xffffu)) + bv.x;
      float fv = g0.y + g1.y + bf2f((unsigned short)(xq.x >> 16)) + bv.y;
      float gv = g0.z + g1.z + bf2f((unsigned short)(xq.y & 0xffffu)) + bv.z;
      float ov = g0.w + g1.w + bf2f((unsigned short)(xq.y >> 16)) + bv.w;
      float ig = sigm(iv), fg = sigm(fv), og = sigm(ov);
      float gt = tanh_fast(gv);
      creg = fg * creg + ig * gt;
      float hn = og * tanh_fast(creg);
      // hnx FIRST (the only store other WGs read), then out
      hnx[oi] = f2bf(hn);
      asm volatile("" ::: "memory");
      out[(size_t)t * BH + oi] = hn;
      if (t == Tt - 1) {
        float* dh = out + (size_t)Tt * BH;
        dh[oi] = hn;        // h_last
        dh[BH + oi] = creg; // c_last
      }
    }

    if (t < Tt - 1) {
      // drain hnx only (oldest); out ack rides under next step's staging
      asm volatile("s_waitcnt vmcnt(1)" ::: "memory");
      __builtin_amdgcn_sched_barrier(0);
      __builtin_amdgcn_s_barrier();   // all waves' hnx in L2
      __builtin_amdgcn_sched_barrier(0);
      if (tid == 0) {
        __hip_atomic_fetch_add(mycnt, 1u, __ATOMIC_RELAXED,
                               __HIP_MEMORY_SCOPE_AGENT);
        unsigned int target = 32u * (unsigned int)(t + 1);
        for (int it = 0; it < (1 << 14); ++it) {
          if (__hip_atomic_load(mycnt, __ATOMIC_RELAXED,
                                __HIP_MEMORY_SCOPE_AGENT) >= target)
            break;
          __builtin_amdgcn_s_sleep(1);
        }
        // L1-only invalidate so this CU's next h loads see fresh L2 data
        asm volatile("buffer_inv sc0" ::: "memory");
      }
      __builtin_amdgcn_sched_barrier(0);
      __builtin_amdgcn_s_barrier();   // release all waves into step t+1
      __builtin_amdgcn_sched_barrier(0);
    }
  }
}

// ====================== OLD PATH (fallback, ws-limited) ======================

__global__ void prep_kernel(const float* __restrict__ Wih,
                            const float* __restrict__ Whh,
                            const float* __restrict__ bias,
                            unsigned short* __restrict__ Wr,
                            float* __restrict__ br,
                            float* __restrict__ c) {
  long tid0 = (long)blockIdx.x * blockDim.x + threadIdx.x;
  long stride = (long)gridDim.x * blockDim.x;
  const long total = (long)NG * KC;
  for (long idx = tid0; idx < total; idx += stride) {
    int n = (int)(idx >> 11);
    int k = (int)(idx & (KC - 1));
    int j = n >> 2, g = n & 3;
    float v;
    if (k < Dd) v = Wih[(size_t)(g * Hh + j) * Dd + k];
    else        v = Whh[(size_t)(g * Hh + j) * Hh + (k - Dd)];
    Wr[idx] = f2bf(v);
  }
  for (long idx = tid0; idx < NG; idx += stride) {
    int j = (int)idx >> 2, g = (int)idx & 3;
    br[idx] = bias[g * Hh + j];
  }
  for (long idx = tid0; idx < (long)Bb * Hh; idx += stride)
    c[idx] = 0.f;
}

__global__ __launch_bounds__(256)
void lstm_step(const float* __restrict__ xt,
               const float* __restrict__ hprev,
               const unsigned short* __restrict__ Wr,
               const float* __restrict__ br,
               float* __restrict__ c,
               float* __restrict__ hout) {
  __shared__ unsigned short As2[32][64 + 8];
  __shared__ unsigned short Bs2[64][64 + 8];
  __shared__ float Gs[32][64];

  const int tid = threadIdx.x;
  const int lane = tid & 63;
  const int wid = tid >> 6;
  const int wr = wid >> 1;
  const int wc = wid & 1;
  const int m0 = blockIdx.x * 32;
  const int n0 = blockIdx.y * 64;

  f32x4 acc0 = {0.f, 0.f, 0.f, 0.f};
  f32x4 acc1 = {0.f, 0.f, 0.f, 0.f};

  const int a_row = tid >> 3;
  const int a_k = (tid & 7) << 3;
  const int b_row = tid >> 2;
  const int b_k = (tid & 3) << 4;

  for (int kc = 0; kc < KC; kc += 64) {
    {
      int k = kc + a_k;
      float v[8];
      if (k < Dd) {
        const float4* s =
            (const float4*)(xt + (size_t)(m0 + a_row) * ((size_t)Tt * Dd) + k);
        float4 p0 = s[0], p1 = s[1];
        v[0] = p0.x; v[1] = p0.y; v[2] = p0.z; v[3] = p0.w;
        v[4] = p1.x; v[5] = p1.y; v[6] = p1.z; v[7] = p1.w;
      } else if (hprev) {
        const float4* s =
            (const float4*)(hprev + (size_t)(m0 + a_row) * Hh + (k - Dd));
        float4 p0 = s[0], p1 = s[1];
        v[0] = p0.x; v[1] = p0.y; v[2] = p0.z; v[3] = p0.w;
        v[4] = p1.x; v[5] = p1.y; v[6] = p1.z; v[7] = p1.w;
      } else {
#pragma unroll
        for (int e = 0; e < 8; e++) v[e] = 0.f;
      }
#pragma unroll
      for (int e = 0; e < 8; e++) As2[a_row][a_k + e] = f2bf(v[e]);
    }
    {
      const uint4* s = (const uint4*)(Wr + (size_t)(n0 + b_row) * KC + kc + b_k);
      uint4 p0 = s[0], p1 = s[1];
      *(uint4*)&Bs2[b_row][b_k] = p0;
      *(uint4*)&Bs2[b_row][b_k + 8] = p1;
    }
    __syncthreads();
#pragma unroll
    for (int ks = 0; ks < 64; ks += 32) {
      s16x8 af = *(const s16x8*)&As2[wr * 16 + (lane & 15)][ks + ((lane >> 4) << 3)];
      s16x8 bf0 = *(const s16x8*)&Bs2[wc * 32 + (lane & 15)][ks + ((lane >> 4) << 3)];
      s16x8 bf1 = *(const s16x8*)&Bs2[wc * 32 + 16 + (lane & 15)][ks + ((lane >> 4) << 3)];
      acc0 = __builtin_amdgcn_mfma_f32_16x16x32_bf16(af, bf0, acc0, 0, 0, 0);
      acc1 = __builtin_amdgcn_mfma_f32_16x16x32_bf16(af, bf1, acc1, 0, 0, 0);
    }
    __syncthreads();
  }

  {
    int colb = wc * 32 + (lane & 15);
    int rbase = wr * 16 + ((lane >> 4) << 2);
#pragma unroll
    for (int r = 0; r < 4; r++) Gs[rbase + r][colb] = acc0[r];
#pragma unroll
    for (int r = 0; r < 4; r++) Gs[rbase + r][colb + 16] = acc1[r];
  }
  __syncthreads();

  for (int e = tid; e < 512; e += 256) {
    int row = e >> 4;
    int jc = e & 15;
    int gi = jc << 2;
    float iv = Gs[row][gi + 0] + br[n0 + gi + 0];
    float fv = Gs[row][gi + 1] + br[n0 + gi + 1];
    float gv = Gs[row][gi + 2] + br[n0 + gi + 2];
    float ov = Gs[row][gi + 3] + br[n0 + gi + 3];
    int gb = m0 + row;
    int j = (n0 >> 2) + jc;
    float cv = c[(size_t)gb * Hh + j];
    float ig = 1.f / (1.f + __expf(-iv));
    float fg = 1.f / (1.f + __expf(-fv));
    float og = 1.f / (1.f + __expf(-ov));
    float gg = tanhf(gv);
    float cn = fg * cv + ig * gg;
    float hn = og * tanhf(cn);
    c[(size_t)gb * Hh + j] = cn;
    hout[(size_t)gb * Hh + j] = hn;
  }
}

__global__ void finalize_kernel(const float* __restrict__ hlast,
                                const float* __restrict__ c,
                                float* __restrict__ dh,
                                float* __restrict__ dc) {
  int i = blockIdx.x * 256 + threadIdx.x;
  if (i < Bb * Hh) {
    dh[i] = hlast[i];
    dc[i] = c[i];
  }
}

// ============================== LAUNCHER =====================================

extern "C" void kernel_launch(void* const* d_in, const int* in_sizes, int n_in,
                              void* d_out, int out_size, void* d_ws, size_t ws_size,
                              hipStream_t stream) {
  const float* x = (const float*)d_in[0];     // [B,T,D]
  const float* Wih = (const float*)d_in[1];   // [4H,D]
  const float* Whh = (const float*)d_in[2];   // [4H,H]
  const float* bias = (const float*)d_in[3];  // [4H]
  float* out = (float*)d_out;                 // [T,B,H] ++ [B,H] ++ [B,H]
  char* ws = (char*)d_ws;

  const size_t WHH_OFF = 0;
  const size_t WIH_OFF = 8ull << 20;
  const size_t BR_OFF = 16ull << 20;
  const size_t H0_OFF = 17ull << 20;
  const size_t H1_OFF = (17ull << 20) + (256ull << 10);
  const size_t CNT_OFF = (17ull << 20) + (512ull << 10);
  const size_t XBF_OFF = 18ull << 20;
  const size_t XBF_SZ = (size_t)Bb * Tt * Dd * 2;          // 128 MB
  const size_t XP_SZ = (size_t)Tt * Bb * NG * 2;           // 512 MB
  const size_t NEED_MID = XBF_OFF + XP_SZ;                 // ~530 MB
  const size_t NEED_FULL = XBF_OFF + XBF_SZ + XP_SZ;       // ~658 MB

  if (ws_size >= NEED_MID) {
    const bool full = (ws_size >= NEED_FULL);
    unsigned short* Whhr = (unsigned short*)(ws + WHH_OFF);
    unsigned short* Wihr = (unsigned short*)(ws + WIH_OFF);
    float* br = (float*)(ws + BR_OFF);
    unsigned short* hb0 = (unsigned short*)(ws + H0_OFF);
    unsigned short* hb1 = (unsigned short*)(ws + H1_OFF);
    unsigned int* cnt = (unsigned int*)(ws + CNT_OFF);   // 8192 uints zeroed
    unsigned short* xbf = full ? (unsigned short*)(ws + XBF_OFF) : nullptr;
    unsigned short* xp =
        (unsigned short*)(ws + XBF_OFF + (full ? XBF_SZ : 0));

    prep_new<<<2048, 256, 0, stream>>>(Wih, Whh, bias, x, Wihr, Whhr, xbf, br,
                                       hb0, cnt);
    if (full)
      xproj_gemm2<<<16384, 256, 0, stream>>>(xbf, Wihr, xp);
    else
      xproj_gemm<<<16384, 256, 0, stream>>>(x, Wihr, xp);
    lstm_persist<<<256, 512, 0, stream>>>(Whhr, br, xp, hb0, hb1, out,
                                          cnt /*claim*/, cnt + 1024 /*scnt*/);
  } else {
    // fallback: round-1 path (16.5 MB ws)
    unsigned short* Wr = (unsigned short*)ws;
    float* br = (float*)(ws + (size_t)NG * KC * 2);
    float* c = (float*)(ws + (size_t)NG * KC * 2 + (size_t)NG * 4);

    prep_kernel<<<1024, 256, 0, stream>>>(Wih, Whh, bias, Wr, br, c);
    dim3 grid(Bb / 32, NG / 64);
    for (int t = 0; t < Tt; t++) {
      const float* xt = x + (size_t)t * Dd;
      const float* hp = (t == 0) ? nullptr : out + (size_t)(t - 1) * Bb * Hh;
      lstm_step<<<grid, 256, 0, stream>>>(xt, hp, Wr, br, c,
                                          out + (size_t)t * Bb * Hh);
    }
    float* dh = out + (size_t)Tt * Bb * Hh;
    finalize_kernel<<<(Bb * Hh + 255) / 256, 256, 0, stream>>>(
        out + (size_t)(Tt - 1) * Bb * Hh, c, dh, dh + (size_t)Bb * Hh);
  }
}

// Round 15
// 1951.330 us; speedup vs baseline: 1.4524x; 1.1391x over previous
//
#include <hip/hip_runtime.h>

// Problem constants
#define Bb 128
#define Tt 512
#define Dd 1024
#define Hh 1024
#define KC 2048   // D + H (old fallback path)
#define NG 4096   // 4*H, gate-interleaved: n = 4*j + g
#define BH (Bb * Hh)

typedef __attribute__((ext_vector_type(4))) float f32x4;
typedef __attribute__((ext_vector_type(8))) short s16x8;

__device__ inline unsigned short f2bf(float f) {
  union { float f; unsigned int u; } x;
  x.f = f;
  unsigned int r = x.u + 0x7fffu + ((x.u >> 16) & 1u);  // RNE
  return (unsigned short)(r >> 16);
}
__device__ inline float bf2f(unsigned short u) {
  union { unsigned int u; float f; } x;
  x.u = ((unsigned int)u) << 16;
  return x.f;
}
__device__ inline float sigm(float x) {
  return __builtin_amdgcn_rcpf(1.f + __expf(-x));
}
__device__ inline float tanh_fast(float x) {
  return 2.f * __builtin_amdgcn_rcpf(1.f + __expf(-2.f * x)) - 1.f;
}
// async 16B global -> LDS (wave-uniform LDS base + lane*16 HW scatter; global
// source address is per-lane)
__device__ __forceinline__ void gl_lds16(void* lds, const void* g) {
  __builtin_amdgcn_global_load_lds(
      (const __attribute__((address_space(1))) unsigned int*)g,
      (__attribute__((address_space(3))) unsigned int*)lds, 16, 0, 0);
}

// ============================== NEW PATH =====================================

// Build gate-interleaved bf16 W_ih / W_hh, reordered bias, optional bf16 copy
// of X, zero h-carrier and counters.
__global__ void prep_new(const float* __restrict__ Wih,
                         const float* __restrict__ Whh,
                         const float* __restrict__ bias,
                         const float* __restrict__ X,
                         unsigned short* __restrict__ Wihr,
                         unsigned short* __restrict__ Whhr,
                         unsigned short* __restrict__ xbf,   // nullable
                         float* __restrict__ br,
                         unsigned short* __restrict__ hbf0,
                         unsigned int* __restrict__ cnt) {
  long tid0 = (long)blockIdx.x * blockDim.x + threadIdx.x;
  long stride = (long)gridDim.x * blockDim.x;
  const long wtot = (long)NG * 1024;
  for (long i = tid0; i < wtot; i += stride) {
    int n = (int)(i >> 10), k = (int)(i & 1023);
    int j = n >> 2, g = n & 3;
    Wihr[i] = f2bf(Wih[(size_t)(g * Hh + j) * Dd + k]);
    Whhr[i] = f2bf(Whh[(size_t)(g * Hh + j) * Hh + k]);
  }
  if (xbf) {
    const long xv = (long)Bb * Tt * Dd / 4;  // float4 count
    const float4* xs = (const float4*)X;
    for (long i = tid0; i < xv; i += stride) {
      float4 v = xs[i];
      unsigned int lo = (unsigned int)f2bf(v.x) | ((unsigned int)f2bf(v.y) << 16);
      unsigned int hi = (unsigned int)f2bf(v.z) | ((unsigned int)f2bf(v.w) << 16);
      uint2 p; p.x = lo; p.y = hi;
      *(uint2*)(xbf + 4 * i) = p;
    }
  }
  for (long i = tid0; i < NG; i += stride) {
    int j = (int)i >> 2, g = (int)i & 3;
    br[i] = bias[g * Hh + j];
  }
  for (long i = tid0; i < (long)Bb * Hh; i += stride) hbf0[i] = 0;
  for (long i = tid0; i < 8192; i += stride) cnt[i] = 0u;
}

// xp = X @ Wihr^T (f32 A staged through registers). Verified rounds 2-14.
__global__ __launch_bounds__(256)
void xproj_gemm(const float* __restrict__ X,
                const unsigned short* __restrict__ Wr,
                unsigned short* __restrict__ xp) {
  __shared__ unsigned short As[128 * 64];
  __shared__ unsigned short Bs[128 * 64];
  const int tid = threadIdx.x;
  const int lane = tid & 63, wave = tid >> 6;
  const int wr = wave >> 1, wc = wave & 1;

  int bid = blockIdx.x;
  int id2 = (bid & 7) * (16384 / 8) + (bid >> 3);
  const int m0 = (id2 >> 5) * 128;
  const int n0 = (id2 & 31) * 128;

  f32x4 acc[4][4];
#pragma unroll
  for (int m = 0; m < 4; m++)
#pragma unroll
    for (int n = 0; n < 4; n++) acc[m][n] = (f32x4){0.f, 0.f, 0.f, 0.f};

  const int arow = tid >> 1, ahalf = tid & 1;
  const float* abase = X + (size_t)(m0 + arow) * 1024 + ahalf * 32;

  for (int kc = 0; kc < 1024; kc += 64) {
#pragma unroll
    for (int r = 0; r < 4; r++) {
      int ch = wave * 4 + r;
      int row = ch * 8 + (lane >> 3);
      int slot = (lane & 7) ^ (row & 7);
      gl_lds16((char*)Bs + ch * 1024,
               Wr + (size_t)(n0 + row) * 1024 + kc + slot * 8);
    }
    float4 av[8];
    const float4* asrc = (const float4*)(abase + kc);
#pragma unroll
    for (int i = 0; i < 8; i++) av[i] = asrc[i];
    unsigned short ab[32];
#pragma unroll
    for (int i = 0; i < 8; i++) {
      ab[i * 4 + 0] = f2bf(av[i].x);
      ab[i * 4 + 1] = f2bf(av[i].y);
      ab[i * 4 + 2] = f2bf(av[i].z);
      ab[i * 4 + 3] = f2bf(av[i].w);
    }
#pragma unroll
    for (int i = 0; i < 4; i++) {
      int slot = (ahalf * 4 + i) ^ (arow & 7);
      *(uint4*)((char*)As + arow * 128 + slot * 16) = *(const uint4*)&ab[i * 8];
    }
    __syncthreads();
#pragma unroll
    for (int ks = 0; ks < 2; ks++) {
      s16x8 af[4], bfr[4];
#pragma unroll
      for (int m = 0; m < 4; m++) {
        int row = wr * 64 + m * 16 + (lane & 15);
        int slot = (ks * 4 + (lane >> 4)) ^ (row & 7);
        af[m] = *(const s16x8*)((const char*)As + row * 128 + slot * 16);
      }
#pragma unroll
      for (int n = 0; n < 4; n++) {
        int row = wc * 64 + n * 16 + (lane & 15);
        int slot = (ks * 4 + (lane >> 4)) ^ (row & 7);
        bfr[n] = *(const s16x8*)((const char*)Bs + row * 128 + slot * 16);
      }
#pragma unroll
      for (int m = 0; m < 4; m++)
#pragma unroll
        for (int n = 0; n < 4; n++)
          acc[m][n] = __builtin_amdgcn_mfma_f32_16x16x32_bf16(af[m], bfr[n],
                                                              acc[m][n], 0, 0, 0);
    }
    __syncthreads();
  }

#pragma unroll
  for (int m = 0; m < 4; m++) {
#pragma unroll
    for (int r = 0; r < 4; r++) {
      int gm = m0 + wr * 64 + m * 16 + ((lane >> 4) << 2) + r;
      int t = gm & (Tt - 1), b = gm >> 9;
      unsigned short* dst =
          xp + ((size_t)t * Bb + b) * NG + n0 + wc * 64 + (lane & 15);
#pragma unroll
      for (int n = 0; n < 4; n++) dst[n * 16] = f2bf(acc[m][n][r]);
    }
  }
}

// xp = Xb @ Wihr^T with BOTH operands staged via swizzled global_load_lds
// (m97 structure). Verified rounds 9-14.
__global__ __launch_bounds__(256)
void xproj_gemm2(const unsigned short* __restrict__ Xb,
                 const unsigned short* __restrict__ Wr,
                 unsigned short* __restrict__ xp) {
  __shared__ unsigned short As[128 * 64];
  __shared__ unsigned short Bs[128 * 64];
  const int tid = threadIdx.x;
  const int lane = tid & 63, wave = tid >> 6;
  const int wr = wave >> 1, wc = wave & 1;

  int bid = blockIdx.x;
  int id2 = (bid & 7) * (16384 / 8) + (bid >> 3);
  const int m0 = (id2 >> 5) * 128;
  const int n0 = (id2 & 31) * 128;

  f32x4 acc[4][4];
#pragma unroll
  for (int m = 0; m < 4; m++)
#pragma unroll
    for (int n = 0; n < 4; n++) acc[m][n] = (f32x4){0.f, 0.f, 0.f, 0.f};

  const int grow = lane >> 3;             // 8 rows per 1KB chunk
  const int gslot = lane & 7;

  for (int kc = 0; kc < 1024; kc += 64) {
#pragma unroll
    for (int r = 0; r < 4; r++) {
      int ch = wave * 4 + r;
      int row = ch * 8 + grow;
      int slot = gslot ^ (row & 7);
      gl_lds16((char*)Bs + ch * 1024,
               Wr + (size_t)(n0 + row) * 1024 + kc + slot * 8);
    }
#pragma unroll
    for (int r = 0; r < 4; r++) {
      int ch = wave * 4 + r;
      int row = ch * 8 + grow;
      int slot = gslot ^ (row & 7);
      gl_lds16((char*)As + ch * 1024,
               Xb + (size_t)(m0 + row) * 1024 + kc + slot * 8);
    }
    __syncthreads();
#pragma unroll
    for (int ks = 0; ks < 2; ks++) {
      s16x8 af[4], bfr[4];
#pragma unroll
      for (int m = 0; m < 4; m++) {
        int row = wr * 64 + m * 16 + (lane & 15);
        int slot = (ks * 4 + (lane >> 4)) ^ (row & 7);
        af[m] = *(const s16x8*)((const char*)As + row * 128 + slot * 16);
      }
#pragma unroll
      for (int n = 0; n < 4; n++) {
        int row = wc * 64 + n * 16 + (lane & 15);
        int slot = (ks * 4 + (lane >> 4)) ^ (row & 7);
        bfr[n] = *(const s16x8*)((const char*)Bs + row * 128 + slot * 16);
      }
#pragma unroll
      for (int m = 0; m < 4; m++)
#pragma unroll
        for (int n = 0; n < 4; n++)
          acc[m][n] = __builtin_amdgcn_mfma_f32_16x16x32_bf16(af[m], bfr[n],
                                                              acc[m][n], 0, 0, 0);
    }
    __syncthreads();
  }

#pragma unroll
  for (int m = 0; m < 4; m++) {
#pragma unroll
    for (int r = 0; r < 4; r++) {
      int gm = m0 + wr * 64 + m * 16 + ((lane >> 4) << 2) + r;
      int t = gm & (Tt - 1), b = gm >> 9;
      unsigned short* dst =
          xp + ((size_t)t * Bb + b) * NG + n0 + wc * 64 + (lane & 15);
#pragma unroll
      for (int n = 0; n < 4; n++) dst[n * 16] = f2bf(acc[m][n][r]);
    }
  }
}

// Persistent LSTM recurrence, XCD-local groups — round-12/14 structure (best
// measured: 1592-1605us) + ONE change: next-step xq prefetch issued AFTER the
// vmcnt(1) hnx-drain, so its ~900cy HBM latency completes under the ~2us sync
// window instead of serializing into the next step's top (straggler-jitter
// fix; round-13's version mis-ordered it before the drain and regressed).
// Everything else verbatim: kh-split compute, single vmcnt(0)+barrier,
// single per-XCD counter with tid0 publish + bounded poll, buffer_inv sc0.
__global__ __launch_bounds__(512, 1)
void lstm_persist(const unsigned short* __restrict__ Whhr,  // [4096][1024] bf16
                  const float* __restrict__ br,             // [4096] reordered
                  const unsigned short* __restrict__ xp,    // [T][128][4096] bf16
                  unsigned short* __restrict__ hb0,         // [128][1024] bf16
                  unsigned short* __restrict__ hb1,
                  float* __restrict__ out,                  // [T][128][1024] ++ dh ++ dc
                  unsigned int* __restrict__ claim,         // [8] spaced 32 uints
                  unsigned int* __restrict__ scnt) {        // [8] spaced 32 uints
  __shared__ __align__(16) char AsB[16 * 2048];  // h tile [16 rows][128 x16B]
  __shared__ float Gs[2][16][132];               // per-k-half gate partials
  __shared__ unsigned int s_slot;

  const int tid = threadIdx.x;
  const int lane = tid & 63, wave = tid >> 6;  // 8 waves
  const int kh = wave >> 2;                    // k-half
  const int nsl = wave & 3;                    // n-slice (32 gate cols)

  // ---- identify XCD, claim an n-slice ----
  int xcd;
  asm volatile("s_getreg_b32 %0, hwreg(HW_REG_XCC_ID)" : "=s"(xcd));
  xcd &= 7;
  if (tid == 0) {
    s_slot = __hip_atomic_fetch_add(claim + xcd * 32, 1u, __ATOMIC_RELAXED,
                                    __HIP_MEMORY_SCOPE_AGENT);
  }
  __syncthreads();
  const unsigned int slotRaw = s_slot;
  if (slotRaw >= 32u) return;  // uneven dispatch: fail fast, don't hang
  const int slot = (int)slotRaw;
  const int m0 = xcd * 16;
  const int n0 = slot * 128;
  unsigned int* mycnt = scnt + xcd * 32;

  // ---- W_hh slices into registers: gate rows n0+nsl*32..+31, k-half kh ----
  s16x8 breg0[16], breg1[16];
  {
    const unsigned short* b0 = Whhr +
        (size_t)(n0 + nsl * 32 + (lane & 15)) * 1024 + kh * 512 +
        ((lane >> 4) << 3);
    const unsigned short* b1 = b0 + 16 * 1024;
#pragma unroll
    for (int ks = 0; ks < 16; ks++) {
      breg0[ks] = *(const s16x8*)(b0 + ks * 32);
      breg1[ks] = *(const s16x8*)(b1 + ks * 32);
    }
  }

  // pointwise mapping: thread -> (row, 1 hidden unit)
  const int prow = tid >> 5;          // 0..15
  const int pu = tid & 31;            // 0..31 hidden unit within slice
  const int jg = (n0 >> 2) + pu;
  const float4 bv = *(const float4*)(br + n0 + 4 * pu);
  float creg = 0.f;
  const unsigned short* xpt = xp + (size_t)(m0 + prow) * NG + n0 + 4 * pu;
  const size_t oi = (size_t)(m0 + prow) * Hh + jg;

  const int arow = lane & 15;
  const int arow7 = arow & 7;
  const int klane = lane >> 4;
  const char* abase = AsB + arow * 2048;

  // prologue: xq for t=0
  uint2 xq = *(const uint2*)xpt;

  for (int t = 0; t < Tt; t++) {
    const unsigned short* hin = (t & 1) ? hb1 : hb0;
    unsigned short* hnx = (t & 1) ? hb0 : hb1;

    // ---- stage h tile (32KB): 32 chunks of 1KB, 4 per wave (R4 order) ----
#pragma unroll
    for (int i = 0; i < 4; i++) {
      int ch = wave * 4 + i;
      int row = ch >> 1, half = ch & 1;
      gl_lds16(AsB + row * 2048 + half * 1024,
               hin + (size_t)(m0 + row) * 1024 +
                   (((half * 64 + lane) ^ (row & 7)) << 3));
    }

    f32x4 acc0 = {0.f, 0.f, 0.f, 0.f};
    f32x4 acc1 = {0.f, 0.f, 0.f, 0.f};

    asm volatile("s_waitcnt vmcnt(0)" ::: "memory");
    __builtin_amdgcn_sched_barrier(0);
    __builtin_amdgcn_s_barrier();
    __builtin_amdgcn_sched_barrier(0);

    // 16 ds_read_b128 (this wave's k-half), each feeding two MFMAs
#pragma unroll
    for (int ks2 = 0; ks2 < 16; ks2++) {
      int ks = kh * 16 + ks2;
      s16x8 af = *(const s16x8*)(abase + (((ks * 4 + klane) ^ arow7) << 4));
      acc0 = __builtin_amdgcn_mfma_f32_16x16x32_bf16(af, breg0[ks2], acc0, 0, 0, 0);
      acc1 = __builtin_amdgcn_mfma_f32_16x16x32_bf16(af, breg1[ks2], acc1, 0, 0, 0);
    }

    // ---- acc -> Gs[kh] (C/D layout: col=lane&15, row=(lane>>4)*4+reg) ----
    {
      int colg = nsl * 32 + (lane & 15);
      int rb = (lane >> 4) << 2;
#pragma unroll
      for (int r = 0; r < 4; r++) Gs[kh][rb + r][colg] = acc0[r];
#pragma unroll
      for (int r = 0; r < 4; r++) Gs[kh][rb + r][colg + 16] = acc1[r];
    }
    __syncthreads();

    // ---- pointwise LSTM: 1 hidden unit per thread, c in register ----
    {
      float4 g0 = *(const float4*)&Gs[0][prow][4 * pu];
      float4 g1 = *(const float4*)&Gs[1][prow][4 * pu];
      float iv = g0.x + g1.x + bf2f((unsigned short)(xq.x & 0xffffu)) + bv.x;
      float fv = g0.y + g1.y + bf2f((unsigned short)(xq.x >> 16)) + bv.y;
      float gv = g0.z + g1.z + bf2f((unsigned short)(xq.y & 0xffffu)) + bv.z;
      float ov = g0.w + g1.w + bf2f((unsigned short)(xq.y >> 16)) + bv.w;
      float ig = sigm(iv), fg = sigm(fv), og = sigm(ov);
      float gt = tanh_fast(gv);
      creg = fg * creg + ig * gt;
      float hn = og * tanh_fast(creg);
      // hnx FIRST (the only store other WGs read), then out
      hnx[oi] = f2bf(hn);
      asm volatile("" ::: "memory");
      out[(size_t)t * BH + oi] = hn;
      if (t == Tt - 1) {
        float* dh = out + (size_t)Tt * BH;
        dh[oi] = hn;        // h_last
        dh[BH + oi] = creg; // c_last
      }
    }

    if (t < Tt - 1) {
      // drain hnx only (oldest of the 2 outstanding stores); out ack rides on
      asm volatile("s_waitcnt vmcnt(1)" ::: "memory");
      __builtin_amdgcn_sched_barrier(0);
      // NOW issue next step's xq: its HBM latency hides under the sync below
      xq = *(const uint2*)(xpt + (size_t)(t + 1) * (Bb * NG));
      __builtin_amdgcn_sched_barrier(0);
      __builtin_amdgcn_s_barrier();   // all waves' hnx in L2
      __builtin_amdgcn_sched_barrier(0);
      if (tid == 0) {
        __hip_atomic_fetch_add(mycnt, 1u, __ATOMIC_RELAXED,
                               __HIP_MEMORY_SCOPE_AGENT);
        unsigned int target = 32u * (unsigned int)(t + 1);
        for (int it = 0; it < (1 << 14); ++it) {
          if (__hip_atomic_load(mycnt, __ATOMIC_RELAXED,
                                __HIP_MEMORY_SCOPE_AGENT) >= target)
            break;
          __builtin_amdgcn_s_sleep(1);
        }
        // L1-only invalidate so this CU's next h loads see fresh L2 data
        asm volatile("buffer_inv sc0" ::: "memory");
      }
      __builtin_amdgcn_sched_barrier(0);
      __builtin_amdgcn_s_barrier();   // release all waves into step t+1
      __builtin_amdgcn_sched_barrier(0);
    }
  }
}

// ====================== OLD PATH (fallback, ws-limited) ======================

__global__ void prep_kernel(const float* __restrict__ Wih,
                            const float* __restrict__ Whh,
                            const float* __restrict__ bias,
                            unsigned short* __restrict__ Wr,
                            float* __restrict__ br,
                            float* __restrict__ c) {
  long tid0 = (long)blockIdx.x * blockDim.x + threadIdx.x;
  long stride = (long)gridDim.x * blockDim.x;
  const long total = (long)NG * KC;
  for (long idx = tid0; idx < total; idx += stride) {
    int n = (int)(idx >> 11);
    int k = (int)(idx & (KC - 1));
    int j = n >> 2, g = n & 3;
    float v;
    if (k < Dd) v = Wih[(size_t)(g * Hh + j) * Dd + k];
    else        v = Whh[(size_t)(g * Hh + j) * Hh + (k - Dd)];
    Wr[idx] = f2bf(v);
  }
  for (long idx = tid0; idx < NG; idx += stride) {
    int j = (int)idx >> 2, g = (int)idx & 3;
    br[idx] = bias[g * Hh + j];
  }
  for (long idx = tid0; idx < (long)Bb * Hh; idx += stride)
    c[idx] = 0.f;
}

__global__ __launch_bounds__(256)
void lstm_step(const float* __restrict__ xt,
               const float* __restrict__ hprev,
               const unsigned short* __restrict__ Wr,
               const float* __restrict__ br,
               float* __restrict__ c,
               float* __restrict__ hout) {
  __shared__ unsigned short As2[32][64 + 8];
  __shared__ unsigned short Bs2[64][64 + 8];
  __shared__ float Gs[32][64];

  const int tid = threadIdx.x;
  const int lane = tid & 63;
  const int wid = tid >> 6;
  const int wr = wid >> 1;
  const int wc = wid & 1;
  const int m0 = blockIdx.x * 32;
  const int n0 = blockIdx.y * 64;

  f32x4 acc0 = {0.f, 0.f, 0.f, 0.f};
  f32x4 acc1 = {0.f, 0.f, 0.f, 0.f};

  const int a_row = tid >> 3;
  const int a_k = (tid & 7) << 3;
  const int b_row = tid >> 2;
  const int b_k = (tid & 3) << 4;

  for (int kc = 0; kc < KC; kc += 64) {
    {
      int k = kc + a_k;
      float v[8];
      if (k < Dd) {
        const float4* s =
            (const float4*)(xt + (size_t)(m0 + a_row) * ((size_t)Tt * Dd) + k);
        float4 p0 = s[0], p1 = s[1];
        v[0] = p0.x; v[1] = p0.y; v[2] = p0.z; v[3] = p0.w;
        v[4] = p1.x; v[5] = p1.y; v[6] = p1.z; v[7] = p1.w;
      } else if (hprev) {
        const float4* s =
            (const float4*)(hprev + (size_t)(m0 + a_row) * Hh + (k - Dd));
        float4 p0 = s[0], p1 = s[1];
        v[0] = p0.x; v[1] = p0.y; v[2] = p0.z; v[3] = p0.w;
        v[4] = p1.x; v[5] = p1.y; v[6] = p1.z; v[7] = p1.w;
      } else {
#pragma unroll
        for (int e = 0; e < 8; e++) v[e] = 0.f;
      }
#pragma unroll
      for (int e = 0; e < 8; e++) As2[a_row][a_k + e] = f2bf(v[e]);
    }
    {
      const uint4* s = (const uint4*)(Wr + (size_t)(n0 + b_row) * KC + kc + b_k);
      uint4 p0 = s[0], p1 = s[1];
      *(uint4*)&Bs2[b_row][b_k] = p0;
      *(uint4*)&Bs2[b_row][b_k + 8] = p1;
    }
    __syncthreads();
#pragma unroll
    for (int ks = 0; ks < 64; ks += 32) {
      s16x8 af = *(const s16x8*)&As2[wr * 16 + (lane & 15)][ks + ((lane >> 4) << 3)];
      s16x8 bf0 = *(const s16x8*)&Bs2[wc * 32 + (lane & 15)][ks + ((lane >> 4) << 3)];
      s16x8 bf1 = *(const s16x8*)&Bs2[wc * 32 + 16 + (lane & 15)][ks + ((lane >> 4) << 3)];
      acc0 = __builtin_amdgcn_mfma_f32_16x16x32_bf16(af, bf0, acc0, 0, 0, 0);
      acc1 = __builtin_amdgcn_mfma_f32_16x16x32_bf16(af, bf1, acc1, 0, 0, 0);
    }
    __syncthreads();
  }

  {
    int colb = wc * 32 + (lane & 15);
    int rbase = wr * 16 + ((lane >> 4) << 2);
#pragma unroll
    for (int r = 0; r < 4; r++) Gs[rbase + r][colb] = acc0[r];
#pragma unroll
    for (int r = 0; r < 4; r++) Gs[rbase + r][colb + 16] = acc1[r];
  }
  __syncthreads();

  for (int e = tid; e < 512; e += 256) {
    int row = e >> 4;
    int jc = e & 15;
    int gi = jc << 2;
    float iv = Gs[row][gi + 0] + br[n0 + gi + 0];
    float fv = Gs[row][gi + 1] + br[n0 + gi + 1];
    float gv = Gs[row][gi + 2] + br[n0 + gi + 2];
    float ov = Gs[row][gi + 3] + br[n0 + gi + 3];
    int gb = m0 + row;
    int j = (n0 >> 2) + jc;
    float cv = c[(size_t)gb * Hh + j];
    float ig = 1.f / (1.f + __expf(-iv));
    float fg = 1.f / (1.f + __expf(-fv));
    float og = 1.f / (1.f + __expf(-ov));
    float gg = tanhf(gv);
    float cn = fg * cv + ig * gg;
    float hn = og * tanhf(cn);
    c[(size_t)gb * Hh + j] = cn;
    hout[(size_t)gb * Hh + j] = hn;
  }
}

__global__ void finalize_kernel(const float* __restrict__ hlast,
                                const float* __restrict__ c,
                                float* __restrict__ dh,
                                float* __restrict__ dc) {
  int i = blockIdx.x * 256 + threadIdx.x;
  if (i < Bb * Hh) {
    dh[i] = hlast[i];
    dc[i] = c[i];
  }
}

// ============================== LAUNCHER =====================================

extern "C" void kernel_launch(void* const* d_in, const int* in_sizes, int n_in,
                              void* d_out, int out_size, void* d_ws, size_t ws_size,
                              hipStream_t stream) {
  const float* x = (const float*)d_in[0];     // [B,T,D]
  const float* Wih = (const float*)d_in[1];   // [4H,D]
  const float* Whh = (const float*)d_in[2];   // [4H,H]
  const float* bias = (const float*)d_in[3];  // [4H]
  float* out = (float*)d_out;                 // [T,B,H] ++ [B,H] ++ [B,H]
  char* ws = (char*)d_ws;

  const size_t WHH_OFF = 0;
  const size_t WIH_OFF = 8ull << 20;
  const size_t BR_OFF = 16ull << 20;
  const size_t H0_OFF = 17ull << 20;
  const size_t H1_OFF = (17ull << 20) + (256ull << 10);
  const size_t CNT_OFF = (17ull << 20) + (512ull << 10);
  const size_t XBF_OFF = 18ull << 20;
  const size_t XBF_SZ = (size_t)Bb * Tt * Dd * 2;          // 128 MB
  const size_t XP_SZ = (size_t)Tt * Bb * NG * 2;           // 512 MB
  const size_t NEED_MID = XBF_OFF + XP_SZ;                 // ~530 MB
  const size_t NEED_FULL = XBF_OFF + XBF_SZ + XP_SZ;       // ~658 MB

  if (ws_size >= NEED_MID) {
    const bool full = (ws_size >= NEED_FULL);
    unsigned short* Whhr = (unsigned short*)(ws + WHH_OFF);
    unsigned short* Wihr = (unsigned short*)(ws + WIH_OFF);
    float* br = (float*)(ws + BR_OFF);
    unsigned short* hb0 = (unsigned short*)(ws + H0_OFF);
    unsigned short* hb1 = (unsigned short*)(ws + H1_OFF);
    unsigned int* cnt = (unsigned int*)(ws + CNT_OFF);   // 8192 uints zeroed
    unsigned short* xbf = full ? (unsigned short*)(ws + XBF_OFF) : nullptr;
    unsigned short* xp =
        (unsigned short*)(ws + XBF_OFF + (full ? XBF_SZ : 0));

    prep_new<<<2048, 256, 0, stream>>>(Wih, Whh, bias, x, Wihr, Whhr, xbf, br,
                                       hb0, cnt);
    if (full)
      xproj_gemm2<<<16384, 256, 0, stream>>>(xbf, Wihr, xp);
    else
      xproj_gemm<<<16384, 256, 0, stream>>>(x, Wihr, xp);
    lstm_persist<<<256, 512, 0, stream>>>(Whhr, br, xp, hb0, hb1, out,
                                          cnt /*claim*/, cnt + 1024 /*scnt*/);
  } else {
    // fallback: round-1 path (16.5 MB ws)
    unsigned short* Wr = (unsigned short*)ws;
    float* br = (float*)(ws + (size_t)NG * KC * 2);
    float* c = (float*)(ws + (size_t)NG * KC * 2 + (size_t)NG * 4);

    prep_kernel<<<1024, 256, 0, stream>>>(Wih, Whh, bias, Wr, br, c);
    dim3 grid(Bb / 32, NG / 64);
    for (int t = 0; t < Tt; t++) {
      const float* xt = x + (size_t)t * Dd;
      const float* hp = (t == 0) ? nullptr : out + (size_t)(t - 1) * Bb * Hh;
      lstm_step<<<grid, 256, 0, stream>>>(xt, hp, Wr, br, c,
                                          out + (size_t)t * Bb * Hh);
    }
    float* dh = out + (size_t)Tt * Bb * Hh;
    finalize_kernel<<<(Bb * Hh + 255) / 256, 256, 0, stream>>>(
        out + (size_t)(Tt - 1) * Bb * Hh, c, dh, dh + (size_t)Bb * Hh);
  }
}